// Round 3
// baseline (5129.473 us; speedup 1.0000x reference)
//
#include <hip/hip_runtime.h>

// ---------------------------------------------------------------------------
// SequenceTaggle: hierarchical GRU (sentence enc -> doc enc) on MI355X.
// V=32000 E=256 H=256 O=2 S=96 T=32 B=32, N = S*B = 3072.
// DEVICE DTYPES: all float tensors are FLOAT32; tokens int32; output float32.
// Internal compute: bf16 MFMA with f32 accumulation (weights converted once
// per launch into workspace; hidden-state buffers bf16).
// ---------------------------------------------------------------------------

typedef __bf16 bf16;
typedef __bf16 bf16x8 __attribute__((ext_vector_type(8)));
typedef __bf16 bf16x4 __attribute__((ext_vector_type(4)));
typedef float  f32x4  __attribute__((ext_vector_type(4)));

static __device__ __forceinline__ f32x4 mfma16(bf16x8 a, bf16x8 b, f32x4 c) {
  // D(16x16) = A(16x32)*B(32x16)+C.
  // A: lane row = lane&15, k = (lane>>4)*8 + j  (8 contiguous k per lane)
  // B: lane col = lane&15, k = (lane>>4)*8 + j
  // D: col = lane&15, row = (lane>>4)*4 + reg   [verified m89/m91 layout]
  return __builtin_amdgcn_mfma_f32_16x16x32_bf16(a, b, c, 0, 0, 0);
}
static __device__ __forceinline__ float sigm(float x) { return 1.f / (1.f + __expf(-x)); }

// f32 -> bf16 weight conversion (n4 = n/4 float4 groups)
__global__ __launch_bounds__(256) void f32_to_bf16(
    const float* __restrict__ s, bf16* __restrict__ d, int n4)
{
  int i = blockIdx.x * 256 + threadIdx.x;
  if (i < n4) {
    float4 v = ((const float4*)s)[i];
    bf16x4 o;
    o[0] = (bf16)v.x; o[1] = (bf16)v.y; o[2] = (bf16)v.z; o[3] = (bf16)v.w;
    ((bf16x4*)d)[i] = o;
  }
}

// ---------------------------------------------------------------------------
// Fused GRU step. One wave = one 16x16 tile of h_new; six MFMA accumulators
// (x@Wi, h@Wh for r/z/n). gridDim.y==2 runs fwd+bwd of a bi-GRU in one launch
// (disjoint outputs). x==nullptr -> gather emb rows (f32) via tok at step t.
// hp==nullptr -> h_prev = 0. x rows stride 256 (bf16); h rows stride hstride.
// Weights bf16 (pre-converted); biases f32.
// Grid: (M/4) blocks x 256 thr; wave -> (row tile = wave>>4, col = wave&15).
// ---------------------------------------------------------------------------
__global__ __launch_bounds__(256) void gru_step(
    const bf16* __restrict__ xF, const bf16* __restrict__ hpF, bf16* __restrict__ hoF,
    const bf16* __restrict__ WiF, const bf16* __restrict__ WhF,
    const float* __restrict__ biF, const float* __restrict__ bhF,
    const bf16* __restrict__ xB, const bf16* __restrict__ hpB, bf16* __restrict__ hoB,
    const bf16* __restrict__ WiB, const bf16* __restrict__ WhB,
    const float* __restrict__ biB, const float* __restrict__ bhB,
    const int* __restrict__ tok, const float* __restrict__ emb, int t, int hstride)
{
  const bf16 *x, *hp, *Wi, *Wh;
  const float *bi, *bh;
  bf16* ho;
  if (blockIdx.y == 0) { x = xF; hp = hpF; ho = hoF; Wi = WiF; Wh = WhF; bi = biF; bh = bhF; }
  else                 { x = xB; hp = hpB; ho = hoB; Wi = WiB; Wh = WhB; bi = biB; bh = bhB; }

  int wave = (threadIdx.x >> 6) + (blockIdx.x << 2);
  int cj   = (wave & 15) << 4;   // hidden column tile base
  int m0   = (wave >> 4) << 4;   // batch-row tile base
  int lane = threadIdx.x & 63;
  int r16  = lane & 15, g4 = lane >> 4;
  int arow = m0 + r16;

  const bf16* wi = Wi + (size_t)(cj + r16) * 256;   // r rows; z +65536, n +131072 elems
  const bf16* wh = Wh + (size_t)(cj + r16) * 256;

  f32x4 ax0 = {0,0,0,0}, ax1 = {0,0,0,0}, ax2 = {0,0,0,0};
  f32x4 ah0 = {0,0,0,0}, ah1 = {0,0,0,0}, ah2 = {0,0,0,0};

  if (x) {
    const bf16* xp = x + (size_t)arow * 256;
#pragma unroll
    for (int kk = 0; kk < 8; kk++) {
      int k0 = kk * 32 + g4 * 8;
      bf16x8 a = *(const bf16x8*)(xp + k0);
      ax0 = mfma16(a, *(const bf16x8*)(wi + k0),          ax0);
      ax1 = mfma16(a, *(const bf16x8*)(wi + 65536 + k0),  ax1);
      ax2 = mfma16(a, *(const bf16x8*)(wi + 131072 + k0), ax2);
    }
  } else {
    // tokens (S,T,B): idx = s*1024 + t*32 + b;  row n = s*32 + b (tok pre-offset)
    int tokid = tok[((arow >> 5) << 10) + (t << 5) + (arow & 31)];
    const float* ep = emb + (size_t)tokid * 256;
#pragma unroll
    for (int kk = 0; kk < 8; kk++) {
      int k0 = kk * 32 + g4 * 8;
      float4 u = *(const float4*)(ep + k0);
      float4 w = *(const float4*)(ep + k0 + 4);
      bf16x8 a;
      a[0] = (bf16)u.x; a[1] = (bf16)u.y; a[2] = (bf16)u.z; a[3] = (bf16)u.w;
      a[4] = (bf16)w.x; a[5] = (bf16)w.y; a[6] = (bf16)w.z; a[7] = (bf16)w.w;
      ax0 = mfma16(a, *(const bf16x8*)(wi + k0),          ax0);
      ax1 = mfma16(a, *(const bf16x8*)(wi + 65536 + k0),  ax1);
      ax2 = mfma16(a, *(const bf16x8*)(wi + 131072 + k0), ax2);
    }
  }
  if (hp) {
    const bf16* hap = hp + (size_t)arow * hstride;
#pragma unroll
    for (int kk = 0; kk < 8; kk++) {
      int k0 = kk * 32 + g4 * 8;
      bf16x8 a = *(const bf16x8*)(hap + k0);
      ah0 = mfma16(a, *(const bf16x8*)(wh + k0),          ah0);
      ah1 = mfma16(a, *(const bf16x8*)(wh + 65536 + k0),  ah1);
      ah2 = mfma16(a, *(const bf16x8*)(wh + 131072 + k0), ah2);
    }
  }

  float bir = bi[cj + r16], biz = bi[256 + cj + r16], bin = bi[512 + cj + r16];
  float bhr = bh[cj + r16], bhz = bh[256 + cj + r16], bhn = bh[512 + cj + r16];

#pragma unroll
  for (int rg = 0; rg < 4; rg++) {
    int orow = m0 + g4 * 4 + rg;
    float r = sigm(ax0[rg] + bir + ah0[rg] + bhr);
    float z = sigm(ax1[rg] + biz + ah1[rg] + bhz);
    float n = tanhf(ax2[rg] + bin + r * (ah2[rg] + bhn));
    float hpv = hp ? (float)hp[(size_t)orow * hstride + cj + r16] : 0.f;
    float hv = (1.f - z) * n + z * hpv;
    ho[(size_t)orow * hstride + cj + r16] = (bf16)hv;
  }
}

// ---------------------------------------------------------------------------
// Row LayerNorm in place (bf16 data, f32 params), wave per row. D in {256,512}.
// ---------------------------------------------------------------------------
__global__ __launch_bounds__(256) void ln_rows(
    bf16* __restrict__ data, const float* __restrict__ gam, const float* __restrict__ bet,
    int rows, int D)
{
  int wid = threadIdx.x >> 6, lane = threadIdx.x & 63;
  int row = (blockIdx.x << 2) + wid;
  if (row >= rows) return;
  bf16* p = data + (size_t)row * D;
  int c = D >> 6;                 // 4 or 8 elems per lane
  float v[8];
  float s = 0.f;
  if (c == 8) {
    bf16x8 t8 = *(const bf16x8*)(p + lane * 8);
#pragma unroll
    for (int j = 0; j < 8; j++) { v[j] = (float)t8[j]; s += v[j]; }
  } else {
    bf16x4 t4 = *(const bf16x4*)(p + lane * 4);
#pragma unroll
    for (int j = 0; j < 4; j++) { v[j] = (float)t4[j]; s += v[j]; }
#pragma unroll
    for (int j = 4; j < 8; j++) v[j] = 0.f;
  }
  float sq = 0.f;
  for (int j = 0; j < c; j++) sq += v[j] * v[j];
  for (int m = 32; m; m >>= 1) { s += __shfl_xor(s, m); sq += __shfl_xor(sq, m); }
  float invD = 1.f / (float)D;
  float mu  = s * invD;
  float var = sq * invD - mu * mu;
  float inv = rsqrtf(fmaxf(var, 0.f) + 1e-5f);
  int base = lane * c;
  for (int j = 0; j < c; j++) {
    float o = (v[j] - mu) * inv * gam[base + j] + bet[base + j];
    p[base + j] = (bf16)o;
  }
}

// ---------------------------------------------------------------------------
// Fused sentence tail, no LDS:
// store[row_base+n,:] = (1/32) * sum_t tanh( LN512(hf[t,n,:]||hb[t,n,:]) @ W^T + b )
// hf/hb: (T, c, 256) bf16. W bf16 (converted); gam/bet/bias f32; store bf16.
// Grid c/16 blocks x 256 thr; wave w -> cols w*64..w*64+63.
// ---------------------------------------------------------------------------
__global__ __launch_bounds__(256) void sent_tail(
    const bf16* __restrict__ hf, const bf16* __restrict__ hb,
    const float* __restrict__ gam, const float* __restrict__ bet,
    const bf16* __restrict__ W, const float* __restrict__ bias,
    bf16* __restrict__ store, int c, int row_base)
{
  int wave = threadIdx.x >> 6;
  int lane = threadIdx.x & 63;
  int r16 = lane & 15, g4 = lane >> 4;
  int r0 = (int)blockIdx.x << 4;           // chunk-local row tile base
  size_t rowoff = (size_t)(r0 + r16) * 256;

  f32x4 ms0 = {0,0,0,0}, ms1 = {0,0,0,0}, ms2 = {0,0,0,0}, ms3 = {0,0,0,0};

  for (int t = 0; t < 32; t++) {
    const bf16* pf = hf + (size_t)t * c * 256 + rowoff;
    const bf16* pb = hb + (size_t)t * c * 256 + rowoff;
    bf16x8 xv[16];
    float s = 0.f, sq = 0.f;
#pragma unroll
    for (int kk = 0; kk < 16; kk++) {
      int k0 = kk * 32 + g4 * 8;
      xv[kk] = (kk < 8) ? *(const bf16x8*)(pf + k0) : *(const bf16x8*)(pb + k0 - 256);
#pragma unroll
      for (int j = 0; j < 8; j++) { float f = (float)xv[kk][j]; s += f; sq += f * f; }
    }
    s  += __shfl_xor(s, 16);  s  += __shfl_xor(s, 32);
    sq += __shfl_xor(sq, 16); sq += __shfl_xor(sq, 32);
    float mu  = s * (1.f / 512.f);
    float var = sq * (1.f / 512.f) - mu * mu;
    float inv = rsqrtf(fmaxf(var, 0.f) + 1e-5f);
#pragma unroll
    for (int kk = 0; kk < 16; kk++) {
      int k0 = kk * 32 + g4 * 8;
      float ga[8], be[8];
      *(float4*)(ga)     = *(const float4*)(gam + k0);
      *(float4*)(ga + 4) = *(const float4*)(gam + k0 + 4);
      *(float4*)(be)     = *(const float4*)(bet + k0);
      *(float4*)(be + 4) = *(const float4*)(bet + k0 + 4);
#pragma unroll
      for (int j = 0; j < 8; j++)
        xv[kk][j] = (bf16)(((float)xv[kk][j] - mu) * inv * ga[j] + be[j]);
    }
#pragma unroll
    for (int tc = 0; tc < 4; tc++) {
      int cj = wave * 64 + tc * 16;
      const bf16* wp = W + (size_t)(cj + r16) * 512;
      f32x4 acc = {0,0,0,0};
#pragma unroll
      for (int kk = 0; kk < 16; kk++)
        acc = mfma16(xv[kk], *(const bf16x8*)(wp + kk * 32 + g4 * 8), acc);
      float bb = bias[cj + r16];
      f32x4* msp = (tc == 0) ? &ms0 : (tc == 1) ? &ms1 : (tc == 2) ? &ms2 : &ms3;
#pragma unroll
      for (int j = 0; j < 4; j++) (*msp)[j] += tanhf(acc[j] + bb);
    }
  }
#pragma unroll
  for (int tc = 0; tc < 4; tc++) {
    int cj = wave * 64 + tc * 16;
    f32x4 ms = (tc == 0) ? ms0 : (tc == 1) ? ms1 : (tc == 2) ? ms2 : ms3;
#pragma unroll
    for (int j = 0; j < 4; j++) {
      int row = row_base + r0 + g4 * 4 + j;
      store[(size_t)row * 256 + cj + r16] = (bf16)(ms[j] * 0.03125f);
    }
  }
}

// out = sigmoid(X(3072x512 bf16) @ W(2x512 f32)^T + b) -> (3072x2) f32
__global__ __launch_bounds__(256) void out_head(
    const bf16* __restrict__ X, const float* __restrict__ W,
    const float* __restrict__ bias, float* __restrict__ out)
{
  __shared__ float w[2][512];
  for (int i = threadIdx.x; i < 1024; i += 256) w[i >> 9][i & 511] = W[i];
  __syncthreads();
  int row = blockIdx.x * 256 + threadIdx.x;
  const bf16* p = X + (size_t)row * 512;
  float a0 = bias[0], a1 = bias[1];
  for (int j = 0; j < 512; j += 8) {
    bf16x8 v = *(const bf16x8*)(p + j);
#pragma unroll
    for (int e = 0; e < 8; e++) { float f = (float)v[e]; a0 += f * w[0][j + e]; a1 += f * w[1][j + e]; }
  }
  out[row * 2 + 0] = sigm(a0);
  out[row * 2 + 1] = sigm(a1);
}

// ---------------------------------------------------------------------------
extern "C" void kernel_launch(void* const* d_in, const int* in_sizes, int n_in,
                              void* d_out, int out_size, void* d_ws, size_t ws_size,
                              hipStream_t stream)
{
  (void)in_sizes; (void)n_in; (void)out_size;
  const int*   tokens = (const int*)d_in[0];
  const float* emb    = (const float*)d_in[1];
  auto fp = [&](int i) { return (const float*)d_in[i]; };
  const float *s_WiF = fp(2),  *s_WhF = fp(3),  *s_biF = fp(4),  *s_bhF = fp(5);
  const float *s_lnF_g = fp(6), *s_lnF_b = fp(7);
  const float *s_Wi_f = fp(8),  *s_Wh_f = fp(9),  *s_bi_f = fp(10), *s_bh_f = fp(11);
  const float *s_Wi_b = fp(12), *s_Wh_b = fp(13), *s_bi_b = fp(14), *s_bh_b = fp(15);
  const float *s_ln_g = fp(16), *s_ln_b = fp(17), *s_linW = fp(18), *s_linb = fp(19);
  const float *dWiF = fp(20), *dWhF = fp(21), *dbiF = fp(22), *dbhF = fp(23);
  const float *d_lnF_g = fp(24), *d_lnF_b = fp(25);
  const float *dWi_f = fp(26), *dWh_f = fp(27), *dbi_f = fp(28), *dbh_f = fp(29);
  const float *dWi_b = fp(30), *dWh_b = fp(31), *dbi_b = fp(32), *dbh_b = fp(33);
  const float *d_ln_g = fp(34), *d_ln_b = fp(35), *out_W = fp(36), *out_b = fp(37);

  const int T = 32, S = 96;
  const int GW = 196608;         // 768*256 elems per GRU weight matrix

  // ---- converted bf16 weights at start of workspace ----
  bf16* wc = (bf16*)d_ws;
  bf16 *c_sWiF = wc,            *c_sWhF = wc + GW;
  bf16 *c_sWif = wc + 2*GW,     *c_sWhf = wc + 3*GW;
  bf16 *c_sWib = wc + 4*GW,     *c_sWhb = wc + 5*GW;
  bf16 *c_dWiF = wc + 6*GW,     *c_dWhF = wc + 7*GW;
  bf16 *c_dWif = wc + 8*GW,     *c_dWhf = wc + 9*GW;
  bf16 *c_dWib = wc + 10*GW,    *c_dWhb = wc + 11*GW;
  bf16 *c_linW = wc + 12*GW;    // 131072 elems
  const size_t WB = (size_t)(12 * GW + 131072) * 2;   // 4,980,736 bytes

  const float* srcs[13] = { s_WiF, s_WhF, s_Wi_f, s_Wh_f, s_Wi_b, s_Wh_b,
                            dWiF, dWhF, dWi_f, dWh_f, dWi_b, dWh_b, s_linW };
  bf16* dsts[13] = { c_sWiF, c_sWhF, c_sWif, c_sWhf, c_sWib, c_sWhb,
                     c_dWiF, c_dWhF, c_dWif, c_dWhf, c_dWib, c_dWhb, c_linW };
  for (int i = 0; i < 13; i++) {
    int n4 = (i == 12 ? 131072 : GW) / 4;
    f32_to_bf16<<<(n4 + 255) / 256, 256, 0, stream>>>(srcs[i], dsts[i], n4);
  }

  // ---- pick sentence chunk size c (rows; multiple of 32 = whole sentences)
  const size_t tailB = ((size_t)3072 * 256 + 3072 * 256 + 3072 * 512) * 2; // 6,291,456
  int c = 3072;
  while (c > 96 && WB + (size_t)3 * T * c * 512 + tailB > ws_size) c >>= 1;

  char* ws = (char*)d_ws + WB;
  bf16* y1    = (bf16*)ws;                                  // (T, c, 256)
  bf16* hf    = (bf16*)(ws + (size_t)1 * T * c * 512);      // (T, c, 256)
  bf16* hb    = (bf16*)(ws + (size_t)2 * T * c * 512);      // (T, c, 256)
  bf16* store = (bf16*)(ws + (size_t)3 * T * c * 512);      // (3072, 256)
  bf16* yd1   = store + (size_t)3072 * 256;                 // (3072, 256)
  bf16* ybid  = yd1   + (size_t)3072 * 256;                 // (3072, 512) f|b

  const size_t cH = (size_t)c * 256;

  // ---- sentence encoder, chunked ----
  for (int base = 0; base < 3072; base += c) {
    const int* tkb = tokens + (size_t)base * 32;            // (base/32) sentences * 1024
    for (int t = 0; t < T; t++) {
      gru_step<<<dim3(c / 4, 1), 256, 0, stream>>>(
          nullptr, t ? y1 + (size_t)(t - 1) * cH : nullptr, y1 + (size_t)t * cH,
          c_sWiF, c_sWhF, s_biF, s_bhF,
          nullptr, nullptr, nullptr, nullptr, nullptr, nullptr, nullptr,
          tkb, emb, t, 256);
    }
    ln_rows<<<(T * c) / 4, 256, 0, stream>>>(y1, s_lnF_g, s_lnF_b, T * c, 256);
    for (int i = 0; i < T; i++) {
      int tb = T - 1 - i;
      gru_step<<<dim3(c / 4, 2), 256, 0, stream>>>(
          y1 + (size_t)i * cH,  i ? hf + (size_t)(i - 1) * cH : nullptr,  hf + (size_t)i * cH,
          c_sWif, c_sWhf, s_bi_f, s_bh_f,
          y1 + (size_t)tb * cH, i ? hb + (size_t)(tb + 1) * cH : nullptr, hb + (size_t)tb * cH,
          c_sWib, c_sWhb, s_bi_b, s_bh_b,
          nullptr, nullptr, 0, 256);
    }
    sent_tail<<<c / 16, 256, 0, stream>>>(hf, hb, s_ln_g, s_ln_b, c_linW, s_linb,
                                          store, c, base);
  }

  // ---- document encoder (batch 32, seq 96) ----
  for (int s = 0; s < S; s++) {
    gru_step<<<dim3(8, 1), 256, 0, stream>>>(
        store + (size_t)s * 32 * 256, s ? yd1 + (size_t)(s - 1) * 32 * 256 : nullptr,
        yd1 + (size_t)s * 32 * 256,
        c_dWiF, c_dWhF, dbiF, dbhF,
        nullptr, nullptr, nullptr, nullptr, nullptr, nullptr, nullptr,
        nullptr, nullptr, 0, 256);
  }
  ln_rows<<<768, 256, 0, stream>>>(yd1, d_lnF_g, d_lnF_b, 3072, 256);
  for (int i = 0; i < S; i++) {
    int sb = S - 1 - i;
    gru_step<<<dim3(8, 2), 256, 0, stream>>>(
        yd1 + (size_t)i * 32 * 256,  i ? ybid + (size_t)(i - 1) * 32 * 512 : nullptr,
        ybid + (size_t)i * 32 * 512,
        c_dWif, c_dWhf, dbi_f, dbh_f,
        yd1 + (size_t)sb * 32 * 256, i ? ybid + (size_t)(sb + 1) * 32 * 512 + 256 : nullptr,
        ybid + (size_t)sb * 32 * 512 + 256,
        c_dWib, c_dWhb, dbi_b, dbh_b,
        nullptr, nullptr, 0, 512);
  }
  ln_rows<<<768, 256, 0, stream>>>(ybid, d_ln_g, d_ln_b, 3072, 512);
  out_head<<<12, 256, 0, stream>>>(ybid, out_W, out_b, (float*)d_out);
}